// Round 2
// baseline (2063.593 us; speedup 1.0000x reference)
//
#include <hip/hip_runtime.h>
#include <cfloat>

#define B_  32
#define D_  256
#define N_  2048
#define K_  512
#define V_  6
#define DN_ (D_*N_)       // 524288
#define DK_ (D_*K_)       // 131072
#define QSZ (B_*D_*N_)    // 16777216
#define TOKSZ (B_*N_)     // 65536
#define TOK_OFF QSZ
#define LOSS_OFF (QSZ + V_*TOKSZ)  // 17170432
#define TN 32
#define NBLK (B_*N_/TN)   // 2048
#define MARGIN 0.05f
#define FCAP 4096

__device__ __forceinline__ unsigned long long shfl_xor_u64(unsigned long long v, int m) {
  int lo = __shfl_xor((int)(unsigned)(v & 0xffffffffull), m, 64);
  int hi = __shfl_xor((int)(unsigned)(v >> 32), m, 64);
  return ((unsigned long long)(unsigned)hi << 32) | (unsigned)lo;
}

// ||e_k||^2 per (v,k); also zero the flag counters (runs before all layers)
__global__ __launch_bounds__(256) void enorm_kernel(const float* __restrict__ emb,
                                                    float* __restrict__ en2,
                                                    int* __restrict__ flagCnt) {
  if (blockIdx.x == 0 && threadIdx.x < V_) flagCnt[threadIdx.x] = 0;
  int t = blockIdx.x * 256 + threadIdx.x;
  if (t >= V_ * K_) return;
  int v = t >> 9, k = t & (K_ - 1);
  const float* e = emb + v * DK_ + k;
  float s = 0.f;
  #pragma unroll 4
  for (int d = 0; d < D_; ++d) { float x = e[d * K_]; s += x * x; }
  en2[t] = s;
}

// One VQ layer: argmin over K, write tokens, update residual in place, loss
// partials, and flag near-tie tokens (gap < MARGIN) for f64 fixup.
__global__ __launch_bounds__(256, 2) void vq_layer(
    const float* __restrict__ resIn, float* __restrict__ resOut,
    const float* __restrict__ emb, const float* __restrict__ en2,
    float* __restrict__ tokOut, float* __restrict__ lossPart,
    int* __restrict__ flagCnt, int* __restrict__ flagList)
{
  __shared__ __align__(16) float rT[D_ * TN];   // 32KB residual tile [d][n]
  __shared__ __align__(16) float eT[16 * K_];   // 32KB emb slab [dd][k]
  __shared__ int   sIdx[TN];
  __shared__ float wred[4];

  const int tid = threadIdx.x;
  const int blk = blockIdx.x;
  const int b   = blk >> 6;
  const int n0  = (blk & 63) * TN;
  const float* resB = resIn + b * DN_ + n0;

  // stage full residual tile [256 d][32 n]
  #pragma unroll
  for (int i = 0; i < 8; ++i) {
    int fi = tid + i * 256;        // 0..2047 float4 index
    int dd = fi >> 3;              // 0..255
    int nn = (fi & 7) << 2;        // 0..28
    *(float4*)(&rT[dd * TN + nn]) = *(const float4*)(resB + dd * N_ + nn);
  }

  float acc[8][8];
  #pragma unroll
  for (int t = 0; t < 8; ++t)
    #pragma unroll
    for (int c = 0; c < 8; ++c) acc[t][c] = 0.f;

  const int w    = tid >> 6;   // wave id: owns tokens 8w..8w+7
  const int lane = tid & 63;   // owns k = 4*lane..+3 and 256+4*lane..+3

  for (int d0 = 0; d0 < D_; d0 += 16) {
    __syncthreads();
    const float4* src = (const float4*)(emb + d0 * K_);
    float4* dst = (float4*)eT;
    #pragma unroll
    for (int i = 0; i < 8; ++i) {
      int fi = tid + i * 256;
      dst[fi] = src[fi];
    }
    __syncthreads();
    #pragma unroll
    for (int dd = 0; dd < 16; ++dd) {
      const float4 rv0 = *(const float4*)(&rT[(d0 + dd) * TN + 8 * w]);
      const float4 rv1 = *(const float4*)(&rT[(d0 + dd) * TN + 8 * w + 4]);
      const float4 ev0 = *(const float4*)(&eT[dd * K_ + 4 * lane]);
      const float4 ev1 = *(const float4*)(&eT[dd * K_ + 256 + 4 * lane]);
      float r8[8] = {rv0.x, rv0.y, rv0.z, rv0.w, rv1.x, rv1.y, rv1.z, rv1.w};
      float e8[8] = {ev0.x, ev0.y, ev0.z, ev0.w, ev1.x, ev1.y, ev1.z, ev1.w};
      #pragma unroll
      for (int t = 0; t < 8; ++t)
        #pragma unroll
        for (int c = 0; c < 8; ++c)
          acc[t][c] += r8[t] * e8[c];
    }
  }

  float en8[8];
  {
    float4 a = *(const float4*)(en2 + 4 * lane);
    float4 bq = *(const float4*)(en2 + 256 + 4 * lane);
    en8[0] = a.x; en8[1] = a.y; en8[2] = a.z; en8[3] = a.w;
    en8[4] = bq.x; en8[5] = bq.y; en8[6] = bq.z; en8[7] = bq.w;
  }
  #pragma unroll
  for (int t = 0; t < 8; ++t) {
    float d8[8];
    unsigned long long best = ~0ull;
    #pragma unroll
    for (int c = 0; c < 8; ++c) {
      float dist = en8[c] - 2.0f * acc[t][c];
      d8[c] = dist;
      unsigned ub = __float_as_uint(dist);
      unsigned msk = (ub & 0x80000000u) ? 0xffffffffu : 0x80000000u;
      ub ^= msk;  // totally ordered unsigned key
      int k = (c < 4) ? (4 * lane + c) : (256 + 4 * lane + (c - 4));
      unsigned long long pk = ((unsigned long long)ub << 32) | (unsigned)k;
      best = (pk < best) ? pk : best;
    }
    #pragma unroll
    for (int m = 32; m >= 1; m >>= 1) {
      unsigned long long o = shfl_xor_u64(best, m);
      best = (o < best) ? o : best;
    }
    const int kwin = (int)(best & 0xffffffffu);
    // second-best distance (excluding the winning index)
    float sec = FLT_MAX;
    #pragma unroll
    for (int c = 0; c < 8; ++c) {
      int k = (c < 4) ? (4 * lane + c) : (256 + 4 * lane + (c - 4));
      if (k != kwin) sec = fminf(sec, d8[c]);
    }
    #pragma unroll
    for (int m = 32; m >= 1; m >>= 1) sec = fminf(sec, __shfl_xor(sec, m, 64));
    if (lane == t) {
      sIdx[8 * w + t] = kwin;
      tokOut[b * N_ + n0 + 8 * w + t] = (float)kwin;
      unsigned kb = (unsigned)(best >> 32);
      unsigned ub = (kb & 0x80000000u) ? (kb ^ 0x80000000u) : ~kb;
      float bestD = __uint_as_float(ub);
      if (sec - bestD < MARGIN) {
        int pos = atomicAdd(flagCnt, 1);
        if (pos < FCAP) flagList[pos] = b * N_ + n0 + 8 * w + t;
      }
    }
  }
  __syncthreads();

  // residual update + commit-loss partial
  const int j = tid & 31;   // token within tile
  const int g = tid >> 5;   // d phase 0..7
  const int myIdx = sIdx[j];
  float lacc = 0.f;
  float* outB = resOut + b * DN_ + n0;
  #pragma unroll 4
  for (int d = g; d < D_; d += 8) {
    float q  = emb[d * K_ + myIdx];
    float rn = rT[d * TN + j] - q;
    outB[d * N_ + j] = rn;
    lacc += rn * rn;
  }
  #pragma unroll
  for (int m = 32; m >= 1; m >>= 1) lacc += __shfl_xor(lacc, m, 64);
  if (lane == 0) wred[w] = lacc;
  __syncthreads();
  if (tid == 0) lossPart[blk] = (wred[0] + wred[1]) + (wred[2] + wred[3]);
}

// Exact f64 re-argmin for flagged near-tie tokens of layer v.
__global__ __launch_bounds__(256) void fixup_kernel(
    const float* __restrict__ inputs, const float* __restrict__ embAll,
    float* __restrict__ res, float* __restrict__ tokens,
    const int* __restrict__ flagList, const int* __restrict__ flagCnt, int v)
{
  __shared__ double rD[D_];
  __shared__ double bd[256];
  __shared__ int    bk[256];
  const int d = threadIdx.x;
  int cnt = flagCnt[0]; if (cnt > FCAP) cnt = FCAP;
  for (int i = blockIdx.x; i < cnt; i += gridDim.x) {
    const int tokId = flagList[i];
    const int b = tokId >> 11, n = tokId & (N_ - 1);
    // exact residual: x - sum of previously chosen codewords
    double r = (double)inputs[b * DN_ + d * N_ + n];
    for (int u = 0; u < v; ++u) {
      int tu = (int)tokens[u * TOKSZ + b * N_ + n];
      r -= (double)embAll[u * DK_ + d * K_ + tu];
    }
    rD[d] = r;
    __syncthreads();
    // all 512 distances in f64; per-thread k = d and d+256 (ascending)
    double best = DBL_MAX; int bestK = 0;
    for (int kk = d; kk < K_; kk += 256) {
      double s = 0.0;
      const float* ec = embAll + v * DK_ + kk;
      #pragma unroll 4
      for (int dd = 0; dd < D_; ++dd) {
        double diff = rD[dd] - (double)ec[dd * K_];
        s = fma(diff, diff, s);
      }
      if (s < best) { best = s; bestK = kk; }
    }
    bd[d] = best; bk[d] = bestK;
    __syncthreads();
    for (int st = 128; st >= 1; st >>= 1) {
      if (d < st) {
        if (bd[d + st] < bd[d] || (bd[d + st] == bd[d] && bk[d + st] < bk[d])) {
          bd[d] = bd[d + st]; bk[d] = bk[d + st];
        }
      }
      __syncthreads();
    }
    const int nk = bk[0];
    const int oldK = (int)tokens[v * TOKSZ + b * N_ + n];
    if (nk != oldK) {
      if (d == 0) tokens[v * TOKSZ + b * N_ + n] = (float)nk;
      res[b * DN_ + d * N_ + n] = (float)(rD[d] - (double)embAll[v * DK_ + d * K_ + nk]);
    }
    __syncthreads();
  }
}

// q_sum = inputs - residual_final (in place in d_out)
__global__ __launch_bounds__(256) void finalize_qsum(const float* __restrict__ inp,
                                                     float* __restrict__ out) {
  const float4* a = (const float4*)inp;
  float4* o = (float4*)out;
  const int total = QSZ / 4;
  for (int i = blockIdx.x * 256 + threadIdx.x; i < total; i += gridDim.x * 256) {
    float4 r = o[i], x = a[i];
    o[i] = make_float4(x.x - r.x, x.y - r.y, x.z - r.z, x.w - r.w);
  }
}

__global__ __launch_bounds__(256) void loss_kernel(const float* __restrict__ part,
                                                   float* __restrict__ out) {
  __shared__ float s[256];
  int tid = threadIdx.x;
  float a = 0.f;
  for (int i = tid; i < V_ * NBLK; i += 256) a += part[i];
  s[tid] = a;
  __syncthreads();
  for (int st = 128; st >= 1; st >>= 1) {
    if (tid < st) s[tid] += s[tid + st];
    __syncthreads();
  }
  if (tid == 0) out[LOSS_OFF] = s[0] * (1.0f / (float)QSZ);
}

extern "C" void kernel_launch(void* const* d_in, const int* in_sizes, int n_in,
                              void* d_out, int out_size, void* d_ws, size_t ws_size,
                              hipStream_t stream) {
  (void)in_sizes; (void)n_in; (void)out_size; (void)ws_size;
  const float* inputs = (const float*)d_in[0];
  const float* emb    = (const float*)d_in[1];
  float* out = (float*)d_out;
  float* en2  = (float*)d_ws;               // V_*K_ floats
  float* part = en2 + V_ * K_;              // V_*NBLK floats
  int*  flagCnt  = (int*)(part + V_ * NBLK);  // V_ ints
  int*  flagList = flagCnt + V_;              // V_*FCAP ints
  float* toks = out + TOK_OFF;

  enorm_kernel<<<(V_ * K_ + 255) / 256, 256, 0, stream>>>(emb, en2, flagCnt);
  for (int v = 0; v < V_; ++v) {
    const float* rin = (v == 0) ? inputs : out;  // residual chained in d_out
    vq_layer<<<NBLK, 256, 0, stream>>>(rin, out, emb + v * DK_, en2 + v * K_,
                                       toks + v * TOKSZ, part + v * NBLK,
                                       flagCnt + v, flagList + v * FCAP);
    fixup_kernel<<<64, 256, 0, stream>>>(inputs, emb, out, toks,
                                         flagList + v * FCAP, flagCnt + v, v);
  }
  finalize_qsum<<<4096, 256, 0, stream>>>(inputs, out);
  loss_kernel<<<1, 256, 0, stream>>>(part, out);
}

// Round 3
// 1750.154 us; speedup vs baseline: 1.1791x; 1.1791x over previous
//
#include <hip/hip_runtime.h>

#define B_  32
#define D_  256
#define N_  2048
#define K_  512
#define V_  6
#define DN_ (D_*N_)        // 524288
#define DK_ (D_*K_)        // 131072
#define QSZ (B_*D_*N_)     // 16777216
#define TOKSZ (B_*N_)      // 65536
#define TOK_OFF QSZ
#define LOSS_OFF (QSZ + V_*TOKSZ)
#define MARGIN 0.02f
#define FCAP 16384
#define NBLK (TOKSZ/64)    // 1024 blocks per layer

typedef __attribute__((ext_vector_type(8))) short short8b;   // 8 bf16 (4 VGPR)
typedef __attribute__((ext_vector_type(4))) float f32x4;

__device__ __forceinline__ unsigned short f2bf(float x) {
  unsigned u = __float_as_uint(x);
  unsigned r = (u + 0x7fffu + ((u >> 16) & 1u)) >> 16;   // RNE
  return (unsigned short)r;
}
__device__ __forceinline__ float bf2f(unsigned short h) {
  return __uint_as_float(((unsigned)h) << 16);
}
__device__ __forceinline__ unsigned orderf(float f) {   // total order as unsigned
  unsigned u = __float_as_uint(f);
  return (u >> 31) ? ~u : (u | 0x80000000u);
}
__device__ __forceinline__ float unorderf(unsigned u) {
  return __uint_as_float((u & 0x80000000u) ? (u & 0x7fffffffu) : ~u);
}
__device__ __forceinline__ unsigned long long shfl_xor_u64(unsigned long long v, int m) {
  int lo = __shfl_xor((int)(unsigned)(v & 0xffffffffull), m, 64);
  int hi = __shfl_xor((int)(unsigned)(v >> 32), m, 64);
  return ((unsigned long long)(unsigned)hi << 32) | (unsigned)lo;
}

// ---- prep: transpose emb[v][d][k] -> Ef32[vk][d] + bf16 hi/lo packs ----
__global__ __launch_bounds__(256) void pack_kernel(const float* __restrict__ emb,
                                                   float* __restrict__ Ef32,
                                                   unsigned short* __restrict__ Ehi,
                                                   unsigned short* __restrict__ Elo) {
  __shared__ float T[64][68];
  const int tid = threadIdx.x;
  const int k0 = blockIdx.x * 64, d0 = blockIdx.y * 64, v = blockIdx.z;
  const float* src = emb + (size_t)v * DK_;
  const int r = tid >> 4, c4 = (tid & 15) * 4;
  #pragma unroll
  for (int i = 0; i < 4; ++i) {
    int d = d0 + r + i * 16;
    float4 x = *(const float4*)(src + (size_t)d * K_ + k0 + c4);
    *(float4*)&T[r + i * 16][c4] = x;
  }
  __syncthreads();
  #pragma unroll
  for (int i = 0; i < 4; ++i) {
    int k = k0 + r + i * 16;
    float4 wv;
    wv.x = T[c4 + 0][r + i * 16];
    wv.y = T[c4 + 1][r + i * 16];
    wv.z = T[c4 + 2][r + i * 16];
    wv.w = T[c4 + 3][r + i * 16];
    size_t o = ((size_t)v * K_ + k) * 256 + d0 + c4;
    *(float4*)(Ef32 + o) = wv;
    ushort4 hv, lv;
    hv.x = f2bf(wv.x); lv.x = f2bf(wv.x - bf2f(hv.x));
    hv.y = f2bf(wv.y); lv.y = f2bf(wv.y - bf2f(hv.y));
    hv.z = f2bf(wv.z); lv.z = f2bf(wv.z - bf2f(hv.z));
    hv.w = f2bf(wv.w); lv.w = f2bf(wv.w - bf2f(hv.w));
    *(ushort4*)(Ehi + o) = hv;
    *(ushort4*)(Elo + o) = lv;
  }
}

// ---- ||e||^2 in f32 and f64 (from packed Ef32, coalesced-ish) ----
__global__ __launch_bounds__(256) void en2_kernel(const float* __restrict__ Ef32,
                                                  float* __restrict__ en2f,
                                                  double* __restrict__ en2d) {
  __shared__ double P[64][4];
  const int tid = threadIdx.x;
  const int k = blockIdx.x * 64 + (tid >> 2), q = tid & 3;
  const float* e = Ef32 + (size_t)k * 256 + q * 64;
  double s = 0.0;
  #pragma unroll 8
  for (int i = 0; i < 64; ++i) { double x = (double)e[i]; s = fma(x, x, s); }
  P[tid >> 2][q] = s;
  __syncthreads();
  if (tid < 64) {
    int k2 = blockIdx.x * 64 + tid;
    double t = (P[tid][0] + P[tid][1]) + (P[tid][2] + P[tid][3]);
    en2d[k2] = t;
    en2f[k2] = (float)t;
  }
}

// ---- inputs[b][d][n] -> Rt[(b*N+n)][d] ----
__global__ __launch_bounds__(256) void transpose_in(const float* __restrict__ in,
                                                    float* __restrict__ Rt) {
  __shared__ float T[64][68];
  const int tid = threadIdx.x;
  const int n0 = blockIdx.x * 64, d0 = blockIdx.y * 64, b = blockIdx.z;
  const float* src = in + (size_t)b * DN_;
  const int r = tid >> 4, c4 = (tid & 15) * 4;
  #pragma unroll
  for (int i = 0; i < 4; ++i) {
    int d = d0 + r + i * 16;
    float4 v = *(const float4*)(src + (size_t)d * N_ + n0 + c4);
    *(float4*)&T[r + i * 16][c4] = v;
  }
  __syncthreads();
  #pragma unroll
  for (int i = 0; i < 4; ++i) {
    int n = n0 + r + i * 16;
    float4 w;
    w.x = T[c4 + 0][r + i * 16];
    w.y = T[c4 + 1][r + i * 16];
    w.z = T[c4 + 2][r + i * 16];
    w.w = T[c4 + 3][r + i * 16];
    *(float4*)(Rt + ((size_t)b * N_ + n) * 256 + d0 + c4) = w;
  }
}

// ---- fused VQ layer: bf16x3 MFMA distances + argmin + update + loss ----
template <bool LAST>
__global__ __launch_bounds__(256, 2) void vq_mfma(
    float* __restrict__ Rt,
    const unsigned short* __restrict__ Ehi, const unsigned short* __restrict__ Elo,
    const float* __restrict__ Ef32v, const float* __restrict__ en2f,
    float* __restrict__ tokOut, float* __restrict__ lossPart,
    int* __restrict__ flagCnt, int* __restrict__ flagList)
{
  __shared__ unsigned short Ahi[4 * 64 * 8];  // [g][tok][8]
  __shared__ unsigned short Alo[4 * 64 * 8];
  __shared__ unsigned long long wmin[4][64];
  __shared__ float wsec[4][64];
  __shared__ int sIdx[64];
  __shared__ float wred[4];

  const int tid = threadIdx.x;
  const int lane = tid & 63, w = tid >> 6;
  const int l15 = lane & 15, lg = lane >> 4;
  const int gt0 = blockIdx.x * 64;
  float* rtBase = Rt + (size_t)gt0 * 256;
  const int kb = w * 128;

  const unsigned short* ehiL = Ehi + (size_t)(kb + l15) * 256 + lg * 8;
  const unsigned short* eloL = Elo + (size_t)(kb + l15) * 256 + lg * 8;

  f32x4 acc[4][8];
  #pragma unroll
  for (int tt = 0; tt < 4; ++tt)
    #pragma unroll
    for (int kt = 0; kt < 8; ++kt) acc[tt][kt] = (f32x4){0.f, 0.f, 0.f, 0.f};

  float en8[8];
  #pragma unroll
  for (int kt = 0; kt < 8; ++kt) en8[kt] = en2f[kb + kt * 16 + l15];

  const int stok = tid >> 2, sg = tid & 3;        // staging: token, d-octet
  const int aIdx = sg * 512 + stok * 8;           // ushort index in A slabs

  for (int c = 0; c < 8; ++c) {
    __syncthreads();
    float4 v0 = *(const float4*)(rtBase + (size_t)stok * 256 + c * 32 + sg * 8);
    float4 v1 = *(const float4*)(rtBase + (size_t)stok * 256 + c * 32 + sg * 8 + 4);
    float xs[8] = {v0.x, v0.y, v0.z, v0.w, v1.x, v1.y, v1.z, v1.w};
    short8b hv, lv;
    #pragma unroll
    for (int j = 0; j < 8; ++j) {
      unsigned short h = f2bf(xs[j]);
      hv[j] = (short)h;
      lv[j] = (short)f2bf(xs[j] - bf2f(h));
    }
    *(short8b*)&Ahi[aIdx] = hv;
    *(short8b*)&Alo[aIdx] = lv;
    __syncthreads();

    short8b ah[4], al[4];
    #pragma unroll
    for (int tt = 0; tt < 4; ++tt) {
      ah[tt] = *(const short8b*)&Ahi[lg * 512 + (tt * 16 + l15) * 8];
      al[tt] = *(const short8b*)&Alo[lg * 512 + (tt * 16 + l15) * 8];
    }
    #pragma unroll
    for (int kt = 0; kt < 8; ++kt) {
      short8b bh = *(const short8b*)(ehiL + (size_t)kt * 4096 + c * 32);
      short8b bl = *(const short8b*)(eloL + (size_t)kt * 4096 + c * 32);
      #pragma unroll
      for (int tt = 0; tt < 4; ++tt) {
        acc[tt][kt] = __builtin_amdgcn_mfma_f32_16x16x32_bf16(ah[tt], bh, acc[tt][kt], 0, 0, 0);
        acc[tt][kt] = __builtin_amdgcn_mfma_f32_16x16x32_bf16(ah[tt], bl, acc[tt][kt], 0, 0, 0);
        acc[tt][kt] = __builtin_amdgcn_mfma_f32_16x16x32_bf16(al[tt], bh, acc[tt][kt], 0, 0, 0);
      }
    }
  }

  // argmin + second-best per token (first-index tie-break like np.argmin)
  #pragma unroll
  for (int tt = 0; tt < 4; ++tt)
    #pragma unroll
    for (int r = 0; r < 4; ++r) {
      const int token = tt * 16 + lg * 4 + r;
      float dv0 = en8[0] - 2.f * acc[tt][0][r];
      unsigned long long p = ((unsigned long long)orderf(dv0) << 32) | (unsigned)(kb + l15);
      float s = 3.402823466e+38f;
      #pragma unroll
      for (int kt = 1; kt < 8; ++kt) {
        float dv = en8[kt] - 2.f * acc[tt][kt][r];
        unsigned long long pk = ((unsigned long long)orderf(dv) << 32) |
                                (unsigned)(kb + kt * 16 + l15);
        if (pk < p) { s = fminf(s, unorderf((unsigned)(p >> 32))); p = pk; }
        else s = fminf(s, dv);
      }
      #pragma unroll
      for (int m = 1; m <= 8; m <<= 1) {
        unsigned long long po = shfl_xor_u64(p, m);
        float so = __shfl_xor(s, m, 64);
        unsigned long long pmax = (po < p) ? p : po;
        s = fminf(fminf(s, so), unorderf((unsigned)(pmax >> 32)));
        p = (po < p) ? po : p;
      }
      if (l15 == 0) { wmin[w][token] = p; wsec[w][token] = s; }
    }
  __syncthreads();
  if (tid < 64) {
    unsigned long long p = wmin[0][tid]; float s = wsec[0][tid];
    #pragma unroll
    for (int w2 = 1; w2 < 4; ++w2) {
      unsigned long long po = wmin[w2][tid]; float so = wsec[w2][tid];
      unsigned long long pmax = (po < p) ? p : po;
      s = fminf(fminf(s, so), unorderf((unsigned)(pmax >> 32)));
      p = (po < p) ? po : p;
    }
    int kwin = (int)(p & 0xffffffffull);
    sIdx[tid] = kwin;
    tokOut[gt0 + tid] = (float)kwin;
    float bd = unorderf((unsigned)(p >> 32));
    if (s - bd < MARGIN) {
      int pos = atomicAdd(flagCnt, 1);
      if (pos < FCAP) flagList[pos] = gt0 + tid;
    }
  }
  __syncthreads();

  // residual update (in place) + loss partial
  const int uj = tid >> 2, udq = (tid & 3) * 64;
  const int kw = sIdx[uj];
  const float* er = Ef32v + (size_t)kw * 256 + udq;
  float* rr = rtBase + (size_t)uj * 256 + udq;
  float lacc = 0.f;
  #pragma unroll
  for (int i = 0; i < 16; ++i) {
    float4 rv = *(const float4*)(rr + i * 4);
    float4 ev = *(const float4*)(er + i * 4);
    float4 rn = make_float4(rv.x - ev.x, rv.y - ev.y, rv.z - ev.z, rv.w - ev.w);
    if (!LAST) *(float4*)(rr + i * 4) = rn;
    lacc += rn.x * rn.x + rn.y * rn.y + rn.z * rn.z + rn.w * rn.w;
  }
  #pragma unroll
  for (int m = 32; m >= 1; m >>= 1) lacc += __shfl_xor(lacc, m, 64);
  if (lane == 0) wred[w] = lacc;
  __syncthreads();
  if (tid == 0) lossPart[blockIdx.x] = (wred[0] + wred[1]) + (wred[2] + wred[3]);
}

// ---- exact f64 re-argmin for flagged near-tie tokens (batched, 8/block-iter) ----
__global__ __launch_bounds__(256) void fixup_kernel(
    const float* __restrict__ inputs, const float* __restrict__ Ef32,
    const double* __restrict__ en2d, float* __restrict__ Rt,
    float* __restrict__ tokens, const int* __restrict__ flagList,
    const int* __restrict__ flagCnt, int v)
{
  __shared__ double rD[8][256];
  __shared__ double sbd[8][32];
  __shared__ int sbk[8][32];
  __shared__ int stok[8];
  const int tid = threadIdx.x;
  int cnt = flagCnt[0]; if (cnt > FCAP) cnt = FCAP;
  const int groups = (cnt + 7) / 8;
  const float* Ev = Ef32 + (size_t)v * DK_;
  for (int g = blockIdx.x; g < groups; g += gridDim.x) {
    if (tid < 8) stok[tid] = (g * 8 + tid < cnt) ? flagList[g * 8 + tid] : -1;
    __syncthreads();
    #pragma unroll
    for (int t = 0; t < 8; ++t) {
      int gt = stok[t];
      if (gt >= 0) {
        int b = gt >> 11, n = gt & (N_ - 1);
        double r = (double)inputs[(size_t)b * DN_ + (size_t)tid * N_ + n];
        for (int u = 0; u < v; ++u) {
          int tu = (int)tokens[u * TOKSZ + gt];
          r -= (double)Ef32[(size_t)u * DK_ + (size_t)tu * 256 + tid];
        }
        rD[t][tid] = r;
      }
    }
    __syncthreads();
    const int tok = tid >> 5, ks = tid & 31;
    double best = 1.0e300; int bkk = 0;
    if (stok[tok] >= 0) {
      for (int kk = ks; kk < K_; kk += 32) {
        const float* ec = Ev + (size_t)kk * 256;
        double dot = 0.0;
        #pragma unroll 8
        for (int dd = 0; dd < 256; ++dd) dot = fma(rD[tok][dd], (double)ec[dd], dot);
        double dist = en2d[v * K_ + kk] - 2.0 * dot;
        if (dist < best) { best = dist; bkk = kk; }
      }
    }
    sbd[tok][ks] = best; sbk[tok][ks] = bkk;
    __syncthreads();
    if (ks == 0 && stok[tok] >= 0) {
      double bb = sbd[tok][0]; int kbb = sbk[tok][0];
      for (int i = 1; i < 32; ++i) {
        if (sbd[tok][i] < bb || (sbd[tok][i] == bb && sbk[tok][i] < kbb)) {
          bb = sbd[tok][i]; kbb = sbk[tok][i];
        }
      }
      int old = (int)tokens[v * TOKSZ + stok[tok]];
      if (kbb != old) tokens[v * TOKSZ + stok[tok]] = (float)kbb;
      sbk[tok][0] = (kbb != old) ? kbb : -1;
    }
    __syncthreads();
    #pragma unroll
    for (int t = 0; t < 8; ++t) {
      int gt = stok[t];
      if (gt >= 0) {
        int nk = sbk[t][0];
        if (nk >= 0)
          Rt[(size_t)gt * 256 + tid] =
              (float)(rD[t][tid] - (double)Ev[(size_t)nk * 256 + tid]);
      }
    }
    __syncthreads();
  }
}

// ---- q_sum[b][d][n] = sum_v Ef32[v][tok_v][d] (reads tokens only) ----
__global__ __launch_bounds__(256) void finalize_q(const float* __restrict__ toks,
                                                  const float* __restrict__ Ef32,
                                                  float* __restrict__ out) {
  const int tid = threadIdx.x;
  const int gt = blockIdx.x * 64 + (tid >> 2);
  const int q = tid & 3;
  const int b = gt >> 11, n = gt & (N_ - 1);
  float4 a[16];
  int k0 = (int)toks[gt];
  const float* e0 = Ef32 + (size_t)k0 * 256 + q * 64;
  #pragma unroll
  for (int i = 0; i < 16; ++i) a[i] = ((const float4*)e0)[i];
  #pragma unroll
  for (int v = 1; v < V_; ++v) {
    int kv = (int)toks[v * TOKSZ + gt];
    const float* ev = Ef32 + (size_t)v * DK_ + (size_t)kv * 256 + q * 64;
    #pragma unroll
    for (int i = 0; i < 16; ++i) {
      float4 e = ((const float4*)ev)[i];
      a[i].x += e.x; a[i].y += e.y; a[i].z += e.z; a[i].w += e.w;
    }
  }
  float* dst = out + (size_t)b * DN_ + n;
  #pragma unroll
  for (int i = 0; i < 16; ++i) {
    int d = q * 64 + i * 4;
    dst[(size_t)(d + 0) * N_] = a[i].x;
    dst[(size_t)(d + 1) * N_] = a[i].y;
    dst[(size_t)(d + 2) * N_] = a[i].z;
    dst[(size_t)(d + 3) * N_] = a[i].w;
  }
}

__global__ __launch_bounds__(256) void loss_kernel(const float* __restrict__ part,
                                                   float* __restrict__ out) {
  __shared__ float s[256];
  const int tid = threadIdx.x;
  float a = 0.f;
  for (int i = tid; i < V_ * NBLK; i += 256) a += part[i];
  s[tid] = a;
  __syncthreads();
  for (int st = 128; st >= 1; st >>= 1) {
    if (tid < st) s[tid] += s[tid + st];
    __syncthreads();
  }
  if (tid == 0) out[LOSS_OFF] = s[0] * (1.0f / (float)QSZ);
}

extern "C" void kernel_launch(void* const* d_in, const int* in_sizes, int n_in,
                              void* d_out, int out_size, void* d_ws, size_t ws_size,
                              hipStream_t stream) {
  (void)in_sizes; (void)n_in; (void)out_size; (void)ws_size;
  const float* inputs = (const float*)d_in[0];
  const float* emb    = (const float*)d_in[1];
  float* out = (float*)d_out;
  char* ws = (char*)d_ws;

  unsigned short* Ehi = (unsigned short*)(ws + 0);          // 1572864 B
  unsigned short* Elo = (unsigned short*)(ws + 1572864);    // 1572864 B
  float*  Ef32 = (float*)(ws + 3145728);                    // 3145728 B
  float*  en2f = (float*)(ws + 6291456);                    // 12288 B
  double* en2d = (double*)(ws + 6303744);                   // 24576 B
  float*  part = (float*)(ws + 6328320);                    // 24576 B
  int*    flagCnt  = (int*)(ws + 6352896);                  // 24 B
  int*    flagList = (int*)(ws + 6352920);                  // 393216 B

  float* Rt   = out;             // residual, transposed [bn][d]
  float* toks = out + TOK_OFF;

  hipMemsetAsync(flagCnt, 0, V_ * sizeof(int), stream);
  pack_kernel<<<dim3(8, 4, 6), 256, 0, stream>>>(emb, Ef32, Ehi, Elo);
  en2_kernel<<<48, 256, 0, stream>>>(Ef32, en2f, en2d);
  transpose_in<<<dim3(32, 4, 32), 256, 0, stream>>>(inputs, Rt);

  for (int v = 0; v < V_; ++v) {
    const unsigned short* ehi = Ehi + (size_t)v * DK_;
    const unsigned short* elo = Elo + (size_t)v * DK_;
    const float* ef = Ef32 + (size_t)v * DK_;
    if (v < V_ - 1)
      vq_mfma<false><<<NBLK, 256, 0, stream>>>(Rt, ehi, elo, ef, en2f + v * K_,
                                               toks + v * TOKSZ, part + v * NBLK,
                                               flagCnt + v, flagList + v * FCAP);
    else
      vq_mfma<true><<<NBLK, 256, 0, stream>>>(Rt, ehi, elo, ef, en2f + v * K_,
                                              toks + v * TOKSZ, part + v * NBLK,
                                              flagCnt + v, flagList + v * FCAP);
    fixup_kernel<<<128, 256, 0, stream>>>(inputs, Ef32, en2d, Rt, toks,
                                          flagList + v * FCAP, flagCnt + v, v);
  }
  finalize_q<<<NBLK, 256, 0, stream>>>(toks, Ef32, out);
  loss_kernel<<<1, 256, 0, stream>>>(part, out);
}

// Round 4
// 879.561 us; speedup vs baseline: 2.3462x; 1.9898x over previous
//
#include <hip/hip_runtime.h>

#define B_  32
#define D_  256
#define N_  2048
#define K_  512
#define V_  6
#define DN_ (D_*N_)        // 524288
#define DK_ (D_*K_)        // 131072
#define QSZ (B_*D_*N_)     // 16777216
#define TOKSZ (B_*N_)      // 65536
#define TOK_OFF QSZ
#define LOSS_OFF (QSZ + V_*TOKSZ)
#define MARGIN 0.02f
#define FCAP 16384
#define NBLK (TOKSZ/64)    // 1024 blocks per layer

typedef __attribute__((ext_vector_type(8))) short short8b;   // 8 bf16 (4 VGPR)
typedef __attribute__((ext_vector_type(4))) float f32x4;

__device__ __forceinline__ unsigned short f2bf(float x) {
  unsigned u = __float_as_uint(x);
  unsigned r = (u + 0x7fffu + ((u >> 16) & 1u)) >> 16;   // RNE
  return (unsigned short)r;
}
__device__ __forceinline__ float bf2f(unsigned short h) {
  return __uint_as_float(((unsigned)h) << 16);
}
__device__ __forceinline__ unsigned orderf(float f) {   // total order as unsigned
  unsigned u = __float_as_uint(f);
  return (u >> 31) ? ~u : (u | 0x80000000u);
}
__device__ __forceinline__ float unorderf(unsigned u) {
  return __uint_as_float((u & 0x80000000u) ? (u & 0x7fffffffu) : ~u);
}
__device__ __forceinline__ unsigned long long shfl_xor_u64(unsigned long long v, int m) {
  int lo = __shfl_xor((int)(unsigned)(v & 0xffffffffull), m, 64);
  int hi = __shfl_xor((int)(unsigned)(v >> 32), m, 64);
  return ((unsigned long long)(unsigned)hi << 32) | (unsigned)lo;
}

// ---- prep: transpose emb[v][d][k] -> Ef32[vk][d] + bf16 hi/lo packs ----
__global__ __launch_bounds__(256) void pack_kernel(const float* __restrict__ emb,
                                                   float* __restrict__ Ef32,
                                                   unsigned short* __restrict__ Ehi,
                                                   unsigned short* __restrict__ Elo) {
  __shared__ float T[64][68];
  const int tid = threadIdx.x;
  const int k0 = blockIdx.x * 64, d0 = blockIdx.y * 64, v = blockIdx.z;
  const float* src = emb + (size_t)v * DK_;
  const int r = tid >> 4, c4 = (tid & 15) * 4;
  #pragma unroll
  for (int i = 0; i < 4; ++i) {
    int d = d0 + r + i * 16;
    float4 x = *(const float4*)(src + (size_t)d * K_ + k0 + c4);
    *(float4*)&T[r + i * 16][c4] = x;
  }
  __syncthreads();
  #pragma unroll
  for (int i = 0; i < 4; ++i) {
    int k = k0 + r + i * 16;
    float4 wv;
    wv.x = T[c4 + 0][r + i * 16];
    wv.y = T[c4 + 1][r + i * 16];
    wv.z = T[c4 + 2][r + i * 16];
    wv.w = T[c4 + 3][r + i * 16];
    size_t o = ((size_t)v * K_ + k) * 256 + d0 + c4;
    *(float4*)(Ef32 + o) = wv;
    ushort4 hv, lv;
    hv.x = f2bf(wv.x); lv.x = f2bf(wv.x - bf2f(hv.x));
    hv.y = f2bf(wv.y); lv.y = f2bf(wv.y - bf2f(hv.y));
    hv.z = f2bf(wv.z); lv.z = f2bf(wv.z - bf2f(hv.z));
    hv.w = f2bf(wv.w); lv.w = f2bf(wv.w - bf2f(hv.w));
    *(ushort4*)(Ehi + o) = hv;
    *(ushort4*)(Elo + o) = lv;
  }
}

// ---- ||e||^2 in f32 and f64 ----
__global__ __launch_bounds__(256) void en2_kernel(const float* __restrict__ Ef32,
                                                  float* __restrict__ en2f,
                                                  double* __restrict__ en2d) {
  __shared__ double P[64][4];
  const int tid = threadIdx.x;
  const int k = blockIdx.x * 64 + (tid >> 2), q = tid & 3;
  const float* e = Ef32 + (size_t)k * 256 + q * 64;
  double s = 0.0;
  #pragma unroll 8
  for (int i = 0; i < 64; ++i) { double x = (double)e[i]; s = fma(x, x, s); }
  P[tid >> 2][q] = s;
  __syncthreads();
  if (tid < 64) {
    int k2 = blockIdx.x * 64 + tid;
    double t = (P[tid][0] + P[tid][1]) + (P[tid][2] + P[tid][3]);
    en2d[k2] = t;
    en2f[k2] = (float)t;
  }
}

// ---- inputs[b][d][n] -> Rt[(b*N+n)][d] ----
__global__ __launch_bounds__(256) void transpose_in(const float* __restrict__ in,
                                                    float* __restrict__ Rt) {
  __shared__ float T[64][68];
  const int tid = threadIdx.x;
  const int n0 = blockIdx.x * 64, d0 = blockIdx.y * 64, b = blockIdx.z;
  const float* src = in + (size_t)b * DN_;
  const int r = tid >> 4, c4 = (tid & 15) * 4;
  #pragma unroll
  for (int i = 0; i < 4; ++i) {
    int d = d0 + r + i * 16;
    float4 v = *(const float4*)(src + (size_t)d * N_ + n0 + c4);
    *(float4*)&T[r + i * 16][c4] = v;
  }
  __syncthreads();
  #pragma unroll
  for (int i = 0; i < 4; ++i) {
    int n = n0 + r + i * 16;
    float4 w;
    w.x = T[c4 + 0][r + i * 16];
    w.y = T[c4 + 1][r + i * 16];
    w.z = T[c4 + 2][r + i * 16];
    w.w = T[c4 + 3][r + i * 16];
    *(float4*)(Rt + ((size_t)b * N_ + n) * 256 + d0 + c4) = w;
  }
}

// ---- fused VQ layer: stage-once bf16x3 MFMA + argmin + update + loss ----
template <bool LAST>
__global__ __launch_bounds__(256, 2) void vq_mfma(
    float* __restrict__ Rt,
    const unsigned short* __restrict__ Ehi, const unsigned short* __restrict__ Elo,
    const float* __restrict__ Ef32v, const float* __restrict__ en2f,
    float* __restrict__ tokOut, float* __restrict__ lossPart,
    int* __restrict__ flagCnt, int* __restrict__ flagList)
{
  __shared__ unsigned short Ahi[8 * 2048];  // [c][g][tok][8]
  __shared__ unsigned short Alo[8 * 2048];
  __shared__ unsigned long long wmin[4][64];
  __shared__ float wsec[4][64];
  __shared__ int sIdx[64];
  __shared__ float wred[4];

  const int tid = threadIdx.x;
  const int lane = tid & 63, w = tid >> 6;
  const int l15 = lane & 15, lg = lane >> 4;
  const int gt0 = blockIdx.x * 64;
  float* rtBase = Rt + (size_t)gt0 * 256;
  const int kb = w * 128;

  const unsigned short* ehiL = Ehi + (size_t)(kb + l15) * 256 + lg * 8;
  const unsigned short* eloL = Elo + (size_t)(kb + l15) * 256 + lg * 8;

  // ---- stage the whole residual tile once: hi/lo bf16 slabs, [c][g][tok][8]
  const int stok = tid >> 2, sg = tid & 3;
  #pragma unroll
  for (int c = 0; c < 8; ++c) {
    float4 v0 = *(const float4*)(rtBase + (size_t)stok * 256 + c * 32 + sg * 8);
    float4 v1 = *(const float4*)(rtBase + (size_t)stok * 256 + c * 32 + sg * 8 + 4);
    float xs[8] = {v0.x, v0.y, v0.z, v0.w, v1.x, v1.y, v1.z, v1.w};
    short8b hv, lv;
    #pragma unroll
    for (int j = 0; j < 8; ++j) {
      unsigned short h = f2bf(xs[j]);
      hv[j] = (short)h;
      lv[j] = (short)f2bf(xs[j] - bf2f(h));
    }
    *(short8b*)&Ahi[c * 2048 + sg * 512 + stok * 8] = hv;
    *(short8b*)&Alo[c * 2048 + sg * 512 + stok * 8] = lv;
  }
  __syncthreads();

  f32x4 acc[4][8];
  #pragma unroll
  for (int tt = 0; tt < 4; ++tt)
    #pragma unroll
    for (int kt = 0; kt < 8; ++kt) acc[tt][kt] = (f32x4){0.f, 0.f, 0.f, 0.f};

  float en8[8];
  #pragma unroll
  for (int kt = 0; kt < 8; ++kt) en8[kt] = en2f[kb + kt * 16 + l15];

  // ---- barrier-free compute: 8 d-chunks, waves free-run
  #pragma unroll
  for (int c = 0; c < 8; ++c) {
    short8b ah[4], al[4];
    #pragma unroll
    for (int tt = 0; tt < 4; ++tt) {
      ah[tt] = *(const short8b*)&Ahi[c * 2048 + lg * 512 + (tt * 16 + l15) * 8];
      al[tt] = *(const short8b*)&Alo[c * 2048 + lg * 512 + (tt * 16 + l15) * 8];
    }
    #pragma unroll
    for (int kt = 0; kt < 8; ++kt) {
      short8b bh = *(const short8b*)(ehiL + (size_t)kt * 4096 + c * 32);
      short8b bl = *(const short8b*)(eloL + (size_t)kt * 4096 + c * 32);
      #pragma unroll
      for (int tt = 0; tt < 4; ++tt) {
        acc[tt][kt] = __builtin_amdgcn_mfma_f32_16x16x32_bf16(ah[tt], bh, acc[tt][kt], 0, 0, 0);
        acc[tt][kt] = __builtin_amdgcn_mfma_f32_16x16x32_bf16(ah[tt], bl, acc[tt][kt], 0, 0, 0);
        acc[tt][kt] = __builtin_amdgcn_mfma_f32_16x16x32_bf16(al[tt], bh, acc[tt][kt], 0, 0, 0);
      }
    }
  }

  // ---- argmin + second-best per token (first-index tie-break)
  #pragma unroll
  for (int tt = 0; tt < 4; ++tt)
    #pragma unroll
    for (int r = 0; r < 4; ++r) {
      const int token = tt * 16 + lg * 4 + r;
      float dv0 = en8[0] - 2.f * acc[tt][0][r];
      unsigned long long p = ((unsigned long long)orderf(dv0) << 32) | (unsigned)(kb + l15);
      float s = 3.402823466e+38f;
      #pragma unroll
      for (int kt = 1; kt < 8; ++kt) {
        float dv = en8[kt] - 2.f * acc[tt][kt][r];
        unsigned long long pk = ((unsigned long long)orderf(dv) << 32) |
                                (unsigned)(kb + kt * 16 + l15);
        if (pk < p) { s = fminf(s, unorderf((unsigned)(p >> 32))); p = pk; }
        else s = fminf(s, dv);
      }
      #pragma unroll
      for (int m = 1; m <= 8; m <<= 1) {
        unsigned long long po = shfl_xor_u64(p, m);
        float so = __shfl_xor(s, m, 64);
        unsigned long long pmax = (po < p) ? p : po;
        s = fminf(fminf(s, so), unorderf((unsigned)(pmax >> 32)));
        p = (po < p) ? po : p;
      }
      if (l15 == 0) { wmin[w][token] = p; wsec[w][token] = s; }
    }
  __syncthreads();
  if (tid < 64) {
    unsigned long long p = wmin[0][tid]; float s = wsec[0][tid];
    #pragma unroll
    for (int w2 = 1; w2 < 4; ++w2) {
      unsigned long long po = wmin[w2][tid]; float so = wsec[w2][tid];
      unsigned long long pmax = (po < p) ? p : po;
      s = fminf(fminf(s, so), unorderf((unsigned)(pmax >> 32)));
      p = (po < p) ? po : p;
    }
    int kwin = (int)(p & 0xffffffffull);
    sIdx[tid] = kwin;
    tokOut[gt0 + tid] = (float)kwin;
    float bd = unorderf((unsigned)(p >> 32));
    if (s - bd < MARGIN) {
      int pos = atomicAdd(flagCnt, 1);
      if (pos < FCAP) flagList[pos] = gt0 + tid;
    }
  }
  __syncthreads();

  // ---- residual update (reconstruct r = hi+lo from LDS; write-only to Rt) + loss
  const int uj = tid >> 2, q = tid & 3;
  const int kw = sIdx[uj];
  const float* er = Ef32v + (size_t)kw * 256 + q * 64;
  float* rr = rtBase + (size_t)uj * 256 + q * 64;
  float lacc = 0.f;
  #pragma unroll
  for (int i = 0; i < 8; ++i) {
    const int c = q * 2 + (i >> 2), g = i & 3;
    short8b h8 = *(const short8b*)&Ahi[c * 2048 + g * 512 + uj * 8];
    short8b l8 = *(const short8b*)&Alo[c * 2048 + g * 512 + uj * 8];
    float4 e0 = *(const float4*)(er + i * 8);
    float4 e1 = *(const float4*)(er + i * 8 + 4);
    float rn[8];
    rn[0] = bf2f((unsigned short)h8[0]) + bf2f((unsigned short)l8[0]) - e0.x;
    rn[1] = bf2f((unsigned short)h8[1]) + bf2f((unsigned short)l8[1]) - e0.y;
    rn[2] = bf2f((unsigned short)h8[2]) + bf2f((unsigned short)l8[2]) - e0.z;
    rn[3] = bf2f((unsigned short)h8[3]) + bf2f((unsigned short)l8[3]) - e0.w;
    rn[4] = bf2f((unsigned short)h8[4]) + bf2f((unsigned short)l8[4]) - e1.x;
    rn[5] = bf2f((unsigned short)h8[5]) + bf2f((unsigned short)l8[5]) - e1.y;
    rn[6] = bf2f((unsigned short)h8[6]) + bf2f((unsigned short)l8[6]) - e1.z;
    rn[7] = bf2f((unsigned short)h8[7]) + bf2f((unsigned short)l8[7]) - e1.w;
    if (!LAST) {
      *(float4*)(rr + i * 8)     = make_float4(rn[0], rn[1], rn[2], rn[3]);
      *(float4*)(rr + i * 8 + 4) = make_float4(rn[4], rn[5], rn[6], rn[7]);
    }
    #pragma unroll
    for (int j = 0; j < 8; ++j) lacc += rn[j] * rn[j];
  }
  #pragma unroll
  for (int m = 32; m >= 1; m >>= 1) lacc += __shfl_xor(lacc, m, 64);
  if (lane == 0) wred[w] = lacc;
  __syncthreads();
  if (tid == 0) lossPart[blockIdx.x] = (wred[0] + wred[1]) + (wred[2] + wred[3]);
}

// ---- exact f64 re-argmin, one flagged token per block-iteration, k-parallel ----
__global__ __launch_bounds__(256) void fixup_kernel(
    const float* __restrict__ inputs, const float* __restrict__ Ef32,
    const double* __restrict__ en2d, float* __restrict__ Rt,
    float* __restrict__ tokens, const int* __restrict__ flagList,
    const int* __restrict__ flagCnt, int v)
{
  __shared__ double rD[256];
  __shared__ double sbd[256];
  __shared__ int sbk[256];
  __shared__ int snk;
  const int tid = threadIdx.x;
  int cnt = flagCnt[0]; if (cnt > FCAP) cnt = FCAP;
  const float* Ev = Ef32 + (size_t)v * DK_;
  for (int i = blockIdx.x; i < cnt; i += gridDim.x) {
    const int gt = flagList[i];
    const int b = gt >> 11, n = gt & (N_ - 1);
    // exact residual for dimension tid
    double r = (double)inputs[(size_t)b * DN_ + (size_t)tid * N_ + n];
    for (int u = 0; u < v; ++u) {
      int tu = (int)tokens[u * TOKSZ + gt];
      r -= (double)Ef32[(size_t)u * DK_ + (size_t)tu * 256 + tid];
    }
    rD[tid] = r;
    __syncthreads();
    // thread handles k = tid and tid+256 (4-way split f64 dot, rD broadcast)
    double best = 1.0e300; int bk = 0;
    #pragma unroll
    for (int half = 0; half < 2; ++half) {
      const int k = tid + half * 256;
      const float* e0 = Ev + (size_t)k * 256;
      double s0 = 0.0, s1 = 0.0, s2 = 0.0, s3 = 0.0;
      #pragma unroll 8
      for (int dd = 0; dd < 256; dd += 4) {
        s0 = fma(rD[dd + 0], (double)e0[dd + 0], s0);
        s1 = fma(rD[dd + 1], (double)e0[dd + 1], s1);
        s2 = fma(rD[dd + 2], (double)e0[dd + 2], s2);
        s3 = fma(rD[dd + 3], (double)e0[dd + 3], s3);
      }
      double dist = en2d[v * K_ + k] - 2.0 * ((s0 + s1) + (s2 + s3));
      if (dist < best) { best = dist; bk = k; }   // k=tid < tid+256: ties keep lower
    }
    sbd[tid] = best; sbk[tid] = bk;
    __syncthreads();
    for (int st = 128; st >= 1; st >>= 1) {
      if (tid < st) {
        double od = sbd[tid + st]; int ok = sbk[tid + st];
        if (od < sbd[tid] || (od == sbd[tid] && ok < sbk[tid])) {
          sbd[tid] = od; sbk[tid] = ok;
        }
      }
      __syncthreads();
    }
    if (tid == 0) {
      int nk = sbk[0];
      int old = (int)tokens[v * TOKSZ + gt];
      if (nk != old) { tokens[v * TOKSZ + gt] = (float)nk; snk = nk; }
      else snk = -1;
    }
    __syncthreads();
    if (snk >= 0)
      Rt[(size_t)gt * 256 + tid] = (float)(rD[tid] - (double)Ev[(size_t)snk * 256 + tid]);
    __syncthreads();
  }
}

// ---- q_sum[b][d][n] = sum_v Ef32[v][tok_v][d] ----
__global__ __launch_bounds__(256) void finalize_q(const float* __restrict__ toks,
                                                  const float* __restrict__ Ef32,
                                                  float* __restrict__ out) {
  const int tid = threadIdx.x;
  const int gt = blockIdx.x * 64 + (tid >> 2);
  const int q = tid & 3;
  const int b = gt >> 11, n = gt & (N_ - 1);
  float4 a[16];
  int k0 = (int)toks[gt];
  const float* e0 = Ef32 + (size_t)k0 * 256 + q * 64;
  #pragma unroll
  for (int i = 0; i < 16; ++i) a[i] = ((const float4*)e0)[i];
  #pragma unroll
  for (int v = 1; v < V_; ++v) {
    int kv = (int)toks[v * TOKSZ + gt];
    const float* ev = Ef32 + (size_t)v * DK_ + (size_t)kv * 256 + q * 64;
    #pragma unroll
    for (int i = 0; i < 16; ++i) {
      float4 e = ((const float4*)ev)[i];
      a[i].x += e.x; a[i].y += e.y; a[i].z += e.z; a[i].w += e.w;
    }
  }
  float* dst = out + (size_t)b * DN_ + n;
  #pragma unroll
  for (int i = 0; i < 16; ++i) {
    int d = q * 64 + i * 4;
    dst[(size_t)(d + 0) * N_] = a[i].x;
    dst[(size_t)(d + 1) * N_] = a[i].y;
    dst[(size_t)(d + 2) * N_] = a[i].z;
    dst[(size_t)(d + 3) * N_] = a[i].w;
  }
}

__global__ __launch_bounds__(256) void loss_kernel(const float* __restrict__ part,
                                                   float* __restrict__ out) {
  __shared__ float s[256];
  const int tid = threadIdx.x;
  float a = 0.f;
  for (int i = tid; i < V_ * NBLK; i += 256) a += part[i];
  s[tid] = a;
  __syncthreads();
  for (int st = 128; st >= 1; st >>= 1) {
    if (tid < st) s[tid] += s[tid + st];
    __syncthreads();
  }
  if (tid == 0) out[LOSS_OFF] = s[0] * (1.0f / (float)QSZ);
}

extern "C" void kernel_launch(void* const* d_in, const int* in_sizes, int n_in,
                              void* d_out, int out_size, void* d_ws, size_t ws_size,
                              hipStream_t stream) {
  (void)in_sizes; (void)n_in; (void)out_size; (void)ws_size;
  const float* inputs = (const float*)d_in[0];
  const float* emb    = (const float*)d_in[1];
  float* out = (float*)d_out;
  char* ws = (char*)d_ws;

  unsigned short* Ehi = (unsigned short*)(ws + 0);          // 1572864 B
  unsigned short* Elo = (unsigned short*)(ws + 1572864);    // 1572864 B
  float*  Ef32 = (float*)(ws + 3145728);                    // 3145728 B
  float*  en2f = (float*)(ws + 6291456);                    // 12288 B
  double* en2d = (double*)(ws + 6303744);                   // 24576 B
  float*  part = (float*)(ws + 6328320);                    // 24576 B
  int*    flagCnt  = (int*)(ws + 6352896);                  // 24 B
  int*    flagList = (int*)(ws + 6352920);                  // 393216 B

  float* Rt   = out;             // residual, transposed [bn][d]
  float* toks = out + TOK_OFF;

  hipMemsetAsync(flagCnt, 0, V_ * sizeof(int), stream);
  pack_kernel<<<dim3(8, 4, 6), 256, 0, stream>>>(emb, Ef32, Ehi, Elo);
  en2_kernel<<<48, 256, 0, stream>>>(Ef32, en2f, en2d);
  transpose_in<<<dim3(32, 4, 32), 256, 0, stream>>>(inputs, Rt);

  for (int v = 0; v < V_; ++v) {
    const unsigned short* ehi = Ehi + (size_t)v * DK_;
    const unsigned short* elo = Elo + (size_t)v * DK_;
    const float* ef = Ef32 + (size_t)v * DK_;
    if (v < V_ - 1)
      vq_mfma<false><<<NBLK, 256, 0, stream>>>(Rt, ehi, elo, ef, en2f + v * K_,
                                               toks + v * TOKSZ, part + v * NBLK,
                                               flagCnt + v, flagList + v * FCAP);
    else
      vq_mfma<true><<<NBLK, 256, 0, stream>>>(Rt, ehi, elo, ef, en2f + v * K_,
                                              toks + v * TOKSZ, part + v * NBLK,
                                              flagCnt + v, flagList + v * FCAP);
    fixup_kernel<<<512, 256, 0, stream>>>(inputs, Ef32, en2d, Rt, toks,
                                          flagList + v * FCAP, flagCnt + v, v);
  }
  finalize_q<<<NBLK, 256, 0, stream>>>(toks, Ef32, out);
  loss_kernel<<<1, 256, 0, stream>>>(part, out);
}